// Round 7
// baseline (1604.394 us; speedup 1.0000x reference)
//
#include <hip/hip_runtime.h>
#include <hip/hip_bf16.h>

typedef unsigned int  uint_t;
typedef unsigned short ushort_t;

#define NN 50000
#define NE 800000
#define NBLK 196   // cdiv(NN,256) for CSR kernels

static inline int cdiv(long long a, long long b) { return (int)((a + b - 1) / b); }

// ---- bf16 pair helpers (element j at low 16 bits) ----
__device__ inline float bflo(uint_t u) { return __uint_as_float(u << 16); }
__device__ inline float bfhi(uint_t u) { return __uint_as_float(u & 0xffff0000u); }
__device__ inline uint_t packbf(float x, float y) {  // RNE
    uint_t xu = __float_as_uint(x), yu = __float_as_uint(y);
    xu += 0x7fffu + ((xu >> 16) & 1u);
    yu += 0x7fffu + ((yu >> 16) & 1u);
    return (xu >> 16) | (yu & 0xffff0000u);
}
__device__ inline ushort_t packbf1(float x) {
    uint_t xu = __float_as_uint(x);
    xu += 0x7fffu + ((xu >> 16) & 1u);
    return (ushort_t)(xu >> 16);
}
__device__ inline uint_t relu_pair(uint_t v) {  // relu both bf16 halves
    uint_t r = v;
    if (r & 0x00008000u) r &= 0xffff0000u;
    if (r & 0x80000000u) r &= 0x0000ffffu;
    return r;
}

// ---------------- CSR build ----------------

__global__ void k_prep(int* __restrict__ deg, float* __restrict__ bnacc) {
    int i = blockIdx.x * blockDim.x + threadIdx.x;
    if (i < NN) deg[i] = 0;
    if (i < 768) bnacc[i] = 0.0f;
}

__global__ void k_hist(const int* __restrict__ dst, int* __restrict__ deg) {
    int e = blockIdx.x * blockDim.x + threadIdx.x;
    if (e < NE) {
        int d = dst[e];
        if ((unsigned)d < NN) atomicAdd(&deg[d], 1);
    }
}

__global__ void k_bsum(const int* __restrict__ deg, int* __restrict__ bsum) {
    __shared__ int l[256];
    int tid = threadIdx.x;
    int i = blockIdx.x * 256 + tid;
    l[tid] = (i < NN) ? deg[i] : 0;
    __syncthreads();
    for (int o = 128; o > 0; o >>= 1) {
        if (tid < o) l[tid] += l[tid + o];
        __syncthreads();
    }
    if (tid == 0) bsum[blockIdx.x] = l[0];
}

__global__ void k_bscan(const int* __restrict__ bsum, int* __restrict__ boff,
                        int* __restrict__ row_ptr) {
    __shared__ int l[256];
    int tid = threadIdx.x;
    int v = (tid < NBLK) ? bsum[tid] : 0;
    l[tid] = v;
    __syncthreads();
    for (int o = 1; o < 256; o <<= 1) {
        int t = (tid >= o) ? l[tid - o] : 0;
        __syncthreads();
        l[tid] += t;
        __syncthreads();
    }
    boff[tid] = l[tid] - v;            // exclusive block offset
    if (tid == 255) row_ptr[NN] = l[255];  // total
}

__global__ void k_rowptr(const int* __restrict__ deg, const int* __restrict__ boff,
                         int* __restrict__ row_ptr, int* __restrict__ cursor,
                         float* __restrict__ dis) {
    __shared__ int l[256];
    int tid = threadIdx.x;
    int i = blockIdx.x * 256 + tid;
    int v = (i < NN) ? deg[i] : 0;
    l[tid] = v;
    __syncthreads();
    for (int o = 1; o < 256; o <<= 1) {
        int t = (tid >= o) ? l[tid - o] : 0;
        __syncthreads();
        l[tid] += t;
        __syncthreads();
    }
    if (i < NN) {
        int excl = boff[blockIdx.x] + l[tid] - v;
        row_ptr[i] = excl;
        cursor[i] = excl;
        dis[i] = rsqrtf((float)(v + 1));  // +1 self-loop
    }
}

__global__ void k_fill(const int* __restrict__ src, const int* __restrict__ dst,
                       const float* __restrict__ dis,
                       int* __restrict__ cursor, int* __restrict__ col,
                       float* __restrict__ wgt) {
    int e = blockIdx.x * blockDim.x + threadIdx.x;
    if (e < NE) {
        int s = src[e], d = dst[e];
        if ((unsigned)s < NN && (unsigned)d < NN) {
            int p = atomicAdd(&cursor[d], 1);
            col[p] = s;
            wgt[p] = dis[s] * dis[d];
        }
    }
}

// ---------------- dense: H = in_tf(X) @ W (+ b) ----------------
// 128 nodes per block, one node per thread. X tile staged coalesced into LDS
// (bf16, relu pre-applied); W half staged fp32 BN-scaled; BN shift folded into
// bias. Per-thread x row held in registers; output transposed through LDS for
// coalesced global stores. blockIdx.y selects output half.
template<int FI, int FO, int IN_BN, int OUT_BIAS, int IN_F32, int OUT_F32>
__global__ __launch_bounds__(128, 2)
void k_dense(const void* __restrict__ Xv, const float* __restrict__ W,
             const float* __restrict__ bnacc, const float* __restrict__ g,
             const float* __restrict__ be, const float* __restrict__ b,
             void* __restrict__ Hv) {
    constexpr int FOH  = FO / 2;              // outputs per block (FO even)
    constexpr int FOHP = (FOH + 3) & ~3;      // padded to multiple of 4
    constexpr int KP   = FI / 2;              // bf16 pairs per row (FI even)
    constexpr int XS_DW  = ((KP + 1) & ~3) | 2;   // x row stride (uints), ==2 mod 4
    constexpr int HPAD   = ((FOH + 1) & ~3) | 2;  // f32 H row stride
    constexpr int XLDS_DW = OUT_F32 ? (XS_DW > HPAD ? XS_DW : HPAD) : XS_DW;

    __shared__ uint_t xlds[128 * XLDS_DW];          // X tile; reused for H out
    __shared__ __align__(16) float wlds[FI * FOHP]; // BN-scaled W half
    __shared__ float biasl[FOHP];
    __shared__ float scl[IN_BN ? FI : 1], shl[IN_BN ? FI : 1];

    int tid  = threadIdx.x;
    int yoff = blockIdx.y * FOH;
    int node0 = blockIdx.x * 128;

    if (IN_BN) {
        if (tid < FI) {
            const float inv_n = 1.0f / NN;
            float mu = bnacc[tid] * inv_n;
            float va = bnacc[96 + tid] * inv_n - mu * mu;
            float r  = rsqrtf(va + 1e-5f);
            float sc = g[tid] * r;
            scl[tid] = sc;
            shl[tid] = be[tid] - mu * sc;
        }
        __syncthreads();
    }

    // stage W half (BN-scaled) into LDS, zero-padded columns
    for (int t = tid; t < FI * FOHP; t += 128) {
        int k = t / FOHP, jp = t - k * FOHP;
        float w = (jp < FOH) ? W[k * FO + yoff + jp] : 0.0f;
        if (IN_BN) w *= scl[k];
        wlds[t] = w;
    }
    // folded bias: b[j] + sum_k shl[k]*W[k][j]
    if (tid < FOHP) {
        float acc = 0.0f;
        if (tid < FOH) {
            if (OUT_BIAS) acc = b[yoff + tid];
            if (IN_BN) {
                #pragma unroll 8
                for (int k = 0; k < FI; ++k) acc = fmaf(shl[k], W[k * FO + yoff + tid], acc);
            }
        }
        biasl[tid] = acc;
    }
    // stage X tile coalesced: bf16 pairs, relu applied when IN_BN
    for (int idx = tid; idx < 128 * KP; idx += 128) {
        int row = idx / KP, c = idx - row * KP;
        int node = node0 + row;
        uint_t v = 0;
        if (node < NN) {
            if (IN_F32) {
                const float* Xg = (const float*)Xv;
                float f0 = Xg[(size_t)node * FI + 2 * c];
                float f1 = Xg[(size_t)node * FI + 2 * c + 1];
                if (IN_BN) { f0 = fmaxf(f0, 0.0f); f1 = fmaxf(f1, 0.0f); }
                v = packbf(f0, f1);
            } else {
                v = ((const uint_t*)Xv)[(size_t)node * KP + c];
                if (IN_BN) v = relu_pair(v);
            }
        }
        xlds[row * XLDS_DW + c] = v;
    }
    __syncthreads();

    int node = node0 + tid;
    bool active = node < NN;

    if (active) {
        // own x row -> registers (LDS, 2-4 way conflicts at padded stride: cheap)
        uint_t xr[KP];
        {
            const uint_t* xrow = &xlds[tid * XLDS_DW];
            #pragma unroll
            for (int c = 0; c + 2 <= KP; c += 2) {
                uint2 v = *(const uint2*)&xrow[c];
                xr[c] = v.x; xr[c + 1] = v.y;
            }
            if (KP & 1) xr[KP - 1] = xrow[KP - 1];
        }
        ushort_t* hrow_us = (ushort_t*)&xlds[tid * XLDS_DW];
        float*    hrow_f  = (float*)&xlds[tid * XLDS_DW];

        #pragma unroll 1
        for (int j0 = 0; j0 < FOHP; j0 += 4) {
            float a[4];
            #pragma unroll
            for (int q = 0; q < 4; ++q) a[q] = biasl[j0 + q];
            #pragma unroll
            for (int kp = 0; kp < KP; ++kp) {
                float xl = bflo(xr[kp]);
                float xh = bfhi(xr[kp]);
                const float4 w0 = *(const float4*)&wlds[(2 * kp) * FOHP + j0];
                const float4 w1 = *(const float4*)&wlds[(2 * kp + 1) * FOHP + j0];
                a[0] = fmaf(xl, w0.x, a[0]); a[1] = fmaf(xl, w0.y, a[1]);
                a[2] = fmaf(xl, w0.z, a[2]); a[3] = fmaf(xl, w0.w, a[3]);
                a[0] = fmaf(xh, w1.x, a[0]); a[1] = fmaf(xh, w1.y, a[1]);
                a[2] = fmaf(xh, w1.z, a[2]); a[3] = fmaf(xh, w1.w, a[3]);
            }
            #pragma unroll
            for (int q = 0; q < 4; ++q) {
                int jp = j0 + q;
                if (jp < FOH) {
                    if (OUT_F32) hrow_f[jp] = a[q];
                    else         hrow_us[jp] = packbf1(a[q]);
                }
            }
        }
    }
    __syncthreads();

    // coalesced copy-out of the H tile
    for (int idx = tid; idx < 128 * FOH; idx += 128) {
        int row = idx / FOH, jj = idx - row * FOH;
        int n = node0 + row;
        if (n < NN) {
            if (OUT_F32) {
                ((float*)Hv)[(size_t)n * FO + yoff + jj] =
                    ((const float*)&xlds[row * XLDS_DW])[jj];
            } else {
                ((ushort_t*)Hv)[(size_t)n * FO + yoff + jj] =
                    ((const ushort_t*)&xlds[row * XLDS_DW])[jj];
            }
        }
    }
}

// ---------------- CSR gather (bf16 in/out, unroll-8) ----------------
template<int FO, int IN_BN, int OUT_BIAS>
__global__ void k_gather(const ushort_t* __restrict__ h, const int* __restrict__ row_ptr,
                         const int* __restrict__ col, const float* __restrict__ wgt,
                         const float* __restrict__ dis,
                         const float* __restrict__ bnacc, const float* __restrict__ g,
                         const float* __restrict__ be,
                         const float* __restrict__ b, ushort_t* __restrict__ A) {
    constexpr int F2 = FO / 2;
    int t = blockIdx.x * blockDim.x + threadIdx.x;
    if (t >= NN * F2) return;
    int i = t / F2;
    int j2 = t - i * F2;
    int j = 2 * j2;

    float sc0 = 1.0f, sh0 = 0.0f, sc1 = 1.0f, sh1 = 0.0f;
    if (IN_BN) {
        const float inv_n = 1.0f / NN;
        float mu0 = bnacc[j] * inv_n;
        float va0 = bnacc[96 + j] * inv_n - mu0 * mu0;
        float r0  = rsqrtf(va0 + 1e-5f);
        sc0 = g[j] * r0; sh0 = be[j] - mu0 * sc0;
        float mu1 = bnacc[j + 1] * inv_n;
        float va1 = bnacc[96 + j + 1] * inv_n - mu1 * mu1;
        float r1  = rsqrtf(va1 + 1e-5f);
        sc1 = g[j + 1] * r1; sh1 = be[j + 1] - mu1 * sc1;
    }

    const uint_t* h2 = (const uint_t*)h + j2;  // column pair j within rows
    float di = dis[i];

    // self-loop
    uint_t su = h2[(size_t)i * F2];
    float vx = bflo(su), vy = bfhi(su);
    if (IN_BN) { vx = fmaxf(vx, 0.0f) * sc0 + sh0; vy = fmaxf(vy, 0.0f) * sc1 + sh1; }
    float ax = vx * di * di;
    float ay = vy * di * di;

    int k = row_ptr[i], end = row_ptr[i + 1];
    for (; k + 8 <= end; k += 8) {
        uint_t uu[8]; float ww[8];
        #pragma unroll
        for (int q = 0; q < 8; ++q) {
            int s = col[k + q];
            ww[q] = wgt[k + q];
            uu[q] = h2[(size_t)s * F2];
        }
        #pragma unroll
        for (int q = 0; q < 8; ++q) {
            float tx = bflo(uu[q]), ty = bfhi(uu[q]);
            if (IN_BN) { tx = fmaxf(tx, 0.0f) * sc0 + sh0; ty = fmaxf(ty, 0.0f) * sc1 + sh1; }
            ax = fmaf(tx, ww[q], ax); ay = fmaf(ty, ww[q], ay);
        }
    }
    for (; k < end; ++k) {
        int s = col[k];
        float w = wgt[k];
        uint_t u = h2[(size_t)s * F2];
        float tx = bflo(u), ty = bfhi(u);
        if (IN_BN) { tx = fmaxf(tx, 0.0f) * sc0 + sh0; ty = fmaxf(ty, 0.0f) * sc1 + sh1; }
        ax = fmaf(tx, w, ax); ay = fmaf(ty, w, ay);
    }
    if (OUT_BIAS) { ax += b[j]; ay += b[j + 1]; }
    ((uint_t*)A)[(size_t)i * F2 + j2] = packbf(ax, ay);
}

// ---------------- BN partial sums over relu(A), bf16 input ----------------
template<int FO>
__global__ void k_bnpart(const ushort_t* __restrict__ A, float* __restrict__ acc) {
    constexpr int F2 = FO / 2;
    __shared__ float ls[96], lq[96];
    int tid = threadIdx.x;
    if (tid < 96) { ls[tid] = 0.0f; lq[tid] = 0.0f; }
    __syncthreads();
    const uint_t* A2 = (const uint_t*)A;
    int t2 = blockIdx.x * blockDim.x + tid;
    int j2 = t2 % F2;
    int stride = gridDim.x * blockDim.x;
    float sx = 0.0f, qx = 0.0f, sy = 0.0f, qy = 0.0f;
    for (; t2 < NN * F2; t2 += stride) {
        uint_t u = A2[t2];
        float x = fmaxf(bflo(u), 0.0f), y = fmaxf(bfhi(u), 0.0f);
        sx += x; qx += x * x;
        sy += y; qy += y * y;
    }
    atomicAdd(&ls[2 * j2], sx);     atomicAdd(&ls[2 * j2 + 1], sy);
    atomicAdd(&lq[2 * j2], qx);     atomicAdd(&lq[2 * j2 + 1], qy);
    __syncthreads();
    if (tid < FO) {
        atomicAdd(&acc[tid], ls[tid]);
        atomicAdd(&acc[96 + tid], lq[tid]);
    }
}

extern "C" void kernel_launch(void* const* d_in, const int* in_sizes, int n_in,
                              void* d_out, int out_size, void* d_ws, size_t ws_size,
                              hipStream_t stream) {
    const float* x = (const float*)d_in[0];
    const int* ei = (const int*)d_in[1];
    const int* src = ei;             // edge_index[0]
    const int* dst = ei + NE;        // edge_index[1]
    const float* W1 = (const float*)d_in[2];  const float* b1 = (const float*)d_in[3];
    const float* W2 = (const float*)d_in[4];  const float* b2 = (const float*)d_in[5];
    const float* W3 = (const float*)d_in[6];  const float* b3 = (const float*)d_in[7];
    const float* W4 = (const float*)d_in[8];  const float* b4 = (const float*)d_in[9];
    const float* W5 = (const float*)d_in[10]; const float* b5 = (const float*)d_in[11];
    const float* W6 = (const float*)d_in[12]; const float* b6 = (const float*)d_in[13];
    const float* g1 = (const float*)d_in[14]; const float* be1 = (const float*)d_in[15];
    const float* g2 = (const float*)d_in[16]; const float* be2 = (const float*)d_in[17];
    const float* g3 = (const float*)d_in[18]; const float* be3 = (const float*)d_in[19];
    const float* g4 = (const float*)d_in[20]; const float* be4 = (const float*)d_in[21];

    // workspace (~21.5 MB)
    float* ws = (float*)d_ws;
    float* dis    = ws;                         // NN
    float* bnacc  = dis + NN;                   // 768
    float* wgt    = bnacc + 768;                // NE
    int* deg      = (int*)(wgt + NE);           // NN
    int* row_ptr  = deg + NN;                   // NN+1
    int* cursor   = row_ptr + NN + 1;           // NN
    int* col      = cursor + NN;                // NE
    int* bsum     = col + NE;                   // 256
    int* boff     = bsum + 256;                 // 256
    ushort_t* hB  = (ushort_t*)(boff + 256);    // NN*70 bf16
    ushort_t* aB  = hB + (size_t)NN * 70;       // NN*70 bf16
    float* out    = (float*)d_out;

    const int NB = 256;
    const dim3 DG(cdiv(NN, 128), 2);
    float* bn0 = bnacc;        // L1 stats (g1,be1)
    float* bn1 = bnacc + 192;  // L2 stats (g2,be2)
    float* bn2 = bnacc + 384;  // L4 stats (g3,be3)
    float* bn3 = bnacc + 576;  // L5 stats (g4,be4)

    // ---- CSR + normalization build ----
    k_prep<<<cdiv(NN, NB), NB, 0, stream>>>(deg, bnacc);
    k_hist<<<cdiv(NE, NB), NB, 0, stream>>>(dst, deg);
    k_bsum<<<NBLK, 256, 0, stream>>>(deg, bsum);
    k_bscan<<<1, 256, 0, stream>>>(bsum, boff, row_ptr);
    k_rowptr<<<NBLK, 256, 0, stream>>>(deg, boff, row_ptr, cursor, dis);
    k_fill<<<cdiv(NE, NB), NB, 0, stream>>>(src, dst, dis, cursor, col, wgt);

    // ---- L1: dense x(88,f32)->hB(70); gather hB -> aB + b1; stats bn0 ----
    k_dense<88, 70, 0, 0, 1, 0><<<DG, 128, 0, stream>>>(x, W1, nullptr, nullptr, nullptr, nullptr, hB);
    k_gather<70, 0, 1><<<cdiv((long long)NN * 35, NB), NB, 0, stream>>>(
        hB, row_ptr, col, wgt, dis, nullptr, nullptr, nullptr, b1, aB);
    k_bnpart<70><<<35 * 56, NB, 0, stream>>>(aB, bn0);

    // ---- L2: dense bn(aB)(70)->hB(60); gather hB -> aB + b2; stats bn1 ----
    k_dense<70, 60, 1, 0, 0, 0><<<DG, 128, 0, stream>>>(aB, W2, bn0, g1, be1, nullptr, hB);
    k_gather<60, 0, 1><<<cdiv((long long)NN * 30, NB), NB, 0, stream>>>(
        hB, row_ptr, col, wgt, dis, nullptr, nullptr, nullptr, b2, aB);
    k_bnpart<60><<<30 * 56, NB, 0, stream>>>(aB, bn1);

    // ---- L3: dense bn(aB)(60)->hB(50); gather hB -> aB + b3 (A3) ----
    k_dense<60, 50, 1, 0, 0, 0><<<DG, 128, 0, stream>>>(aB, W3, bn1, g2, be2, nullptr, hB);
    k_gather<50, 0, 1><<<cdiv((long long)NN * 25, NB), NB, 0, stream>>>(
        hB, row_ptr, col, wgt, dis, nullptr, nullptr, nullptr, b3, aB);

    // ---- L4 (aggregate-first): gather aB(A3) -> hB(agg4,50); dense hB -> aB(A4,60)+b4; stats bn2 ----
    k_gather<50, 0, 0><<<cdiv((long long)NN * 25, NB), NB, 0, stream>>>(
        aB, row_ptr, col, wgt, dis, nullptr, nullptr, nullptr, nullptr, hB);
    k_dense<50, 60, 0, 1, 0, 0><<<DG, 128, 0, stream>>>(hB, W4, nullptr, nullptr, nullptr, b4, aB);
    k_bnpart<60><<<30 * 56, NB, 0, stream>>>(aB, bn2);

    // ---- L5: gather bn(aB=A4) -> hB(agg5,60); dense hB -> aB(A5,70)+b5; stats bn3 ----
    k_gather<60, 1, 0><<<cdiv((long long)NN * 30, NB), NB, 0, stream>>>(
        aB, row_ptr, col, wgt, dis, bn2, g3, be3, nullptr, hB);
    k_dense<60, 70, 0, 1, 0, 0><<<DG, 128, 0, stream>>>(hB, W5, nullptr, nullptr, nullptr, b5, aB);
    k_bnpart<70><<<35 * 56, NB, 0, stream>>>(aB, bn3);

    // ---- L6: gather bn(aB=A5) -> hB(agg6,70); dense hB -> out(88,f32)+b6 ----
    k_gather<70, 1, 0><<<cdiv((long long)NN * 35, NB), NB, 0, stream>>>(
        aB, row_ptr, col, wgt, dis, bn3, g4, be4, nullptr, hB);
    k_dense<70, 88, 0, 1, 0, 1><<<DG, 128, 0, stream>>>(hB, W6, nullptr, nullptr, nullptr, b6, out);
}

// Round 8
// 664.070 us; speedup vs baseline: 2.4160x; 2.4160x over previous
//
#include <hip/hip_runtime.h>
#include <hip/hip_bf16.h>

typedef unsigned int  uint_t;
typedef unsigned short ushort_t;

#define NN 50000
#define NE 800000
#define NBLK 196   // cdiv(NN,256) for CSR kernels

static inline int cdiv(long long a, long long b) { return (int)((a + b - 1) / b); }

// ---- bf16 pair helpers (element j at low 16 bits) ----
__device__ inline float bflo(uint_t u) { return __uint_as_float(u << 16); }
__device__ inline float bfhi(uint_t u) { return __uint_as_float(u & 0xffff0000u); }
__device__ inline uint_t packbf(float x, float y) {  // RNE
    uint_t xu = __float_as_uint(x), yu = __float_as_uint(y);
    xu += 0x7fffu + ((xu >> 16) & 1u);
    yu += 0x7fffu + ((yu >> 16) & 1u);
    return (xu >> 16) | (yu & 0xffff0000u);
}
__device__ inline ushort_t packbf1(float x) {
    uint_t xu = __float_as_uint(x);
    xu += 0x7fffu + ((xu >> 16) & 1u);
    return (ushort_t)(xu >> 16);
}

// ---------------- CSR build ----------------

__global__ void k_prep(int* __restrict__ deg, float* __restrict__ bnacc) {
    int i = blockIdx.x * blockDim.x + threadIdx.x;
    if (i < NN) deg[i] = 0;
    if (i < 768) bnacc[i] = 0.0f;
}

__global__ void k_hist(const int* __restrict__ dst, int* __restrict__ deg) {
    int e = blockIdx.x * blockDim.x + threadIdx.x;
    if (e < NE) {
        int d = dst[e];
        if ((unsigned)d < NN) atomicAdd(&deg[d], 1);
    }
}

__global__ void k_bsum(const int* __restrict__ deg, int* __restrict__ bsum) {
    __shared__ int l[256];
    int tid = threadIdx.x;
    int i = blockIdx.x * 256 + tid;
    l[tid] = (i < NN) ? deg[i] : 0;
    __syncthreads();
    for (int o = 128; o > 0; o >>= 1) {
        if (tid < o) l[tid] += l[tid + o];
        __syncthreads();
    }
    if (tid == 0) bsum[blockIdx.x] = l[0];
}

__global__ void k_bscan(const int* __restrict__ bsum, int* __restrict__ boff,
                        int* __restrict__ row_ptr) {
    __shared__ int l[256];
    int tid = threadIdx.x;
    int v = (tid < NBLK) ? bsum[tid] : 0;
    l[tid] = v;
    __syncthreads();
    for (int o = 1; o < 256; o <<= 1) {
        int t = (tid >= o) ? l[tid - o] : 0;
        __syncthreads();
        l[tid] += t;
        __syncthreads();
    }
    boff[tid] = l[tid] - v;            // exclusive block offset
    if (tid == 255) row_ptr[NN] = l[255];  // total
}

__global__ void k_rowptr(const int* __restrict__ deg, const int* __restrict__ boff,
                         int* __restrict__ row_ptr, int* __restrict__ cursor,
                         float* __restrict__ dis) {
    __shared__ int l[256];
    int tid = threadIdx.x;
    int i = blockIdx.x * 256 + tid;
    int v = (i < NN) ? deg[i] : 0;
    l[tid] = v;
    __syncthreads();
    for (int o = 1; o < 256; o <<= 1) {
        int t = (tid >= o) ? l[tid - o] : 0;
        __syncthreads();
        l[tid] += t;
        __syncthreads();
    }
    if (i < NN) {
        int excl = boff[blockIdx.x] + l[tid] - v;
        row_ptr[i] = excl;
        cursor[i] = excl;
        dis[i] = rsqrtf((float)(v + 1));  // +1 self-loop
    }
}

__global__ void k_fill(const int* __restrict__ src, const int* __restrict__ dst,
                       const float* __restrict__ dis,
                       int* __restrict__ cursor, int* __restrict__ col,
                       float* __restrict__ wgt) {
    int e = blockIdx.x * blockDim.x + threadIdx.x;
    if (e < NE) {
        int s = src[e], d = dst[e];
        if ((unsigned)s < NN && (unsigned)d < NN) {
            int p = atomicAdd(&cursor[d], 1);
            col[p] = s;
            wgt[p] = dis[s] * dis[d];
        }
    }
}

// ---------------- per-layer weight fold/pad ----------------
// Wp layout: k-pair interleaved, padded to FOP=16*NT columns:
//   Wp[(k/2)*2*FOP + 2*j + (k&1)] = W[k][j] * (IN_BN ? scl[k] : 1), j<FO else 0
// biasf[j] = (OUT_B ? b[j] : 0) + (IN_BN ? sum_k shl[k]*W[k][j] : 0)
template<int FI, int FO, int IN_BN, int OUT_B>
__global__ void k_fold(const float* __restrict__ bnacc, const float* __restrict__ g,
                       const float* __restrict__ be, const float* __restrict__ b,
                       const float* __restrict__ W,
                       float* __restrict__ Wp, float* __restrict__ biasf) {
    constexpr int NT  = (FO + 15) / 16;
    constexpr int FOP = 16 * NT;
    __shared__ float scl[IN_BN ? FI : 1], shl[IN_BN ? FI : 1];
    int tid = threadIdx.x;
    if (IN_BN) {
        if (tid < FI) {
            const float inv_n = 1.0f / NN;
            float mu = bnacc[tid] * inv_n;
            float va = bnacc[96 + tid] * inv_n - mu * mu;
            float r  = rsqrtf(va + 1e-5f);
            float sc = g[tid] * r;
            scl[tid] = sc;
            shl[tid] = be[tid] - mu * sc;
        }
        __syncthreads();
    }
    for (int idx = tid; idx < FI * FOP; idx += 256) {
        int k = idx / FOP, j = idx - k * FOP;
        float w = (j < FO) ? W[k * FO + j] : 0.0f;
        if (IN_BN) w *= scl[k];
        Wp[(k >> 1) * 2 * FOP + 2 * j + (k & 1)] = w;
    }
    if (tid < FOP) {
        float a = (OUT_B && tid < FO) ? b[tid] : 0.0f;
        if (IN_BN && tid < FO) {
            #pragma unroll 4
            for (int k = 0; k < FI; ++k) a = fmaf(shl[k], W[k * FO + tid], a);
        }
        biasf[tid] = a;
    }
}

// ---------------- dense: H = in_tf(X) @ Wp + biasf ----------------
// 64 nodes per block, 256 threads. X tile staged fp32 in LDS (coalesced,
// relu applied when IN_BN; scale/shift pre-folded into Wp/biasf by k_fold).
// Thread (ng=tid/16, cg=tid%16) computes nodes {ng,ng+16,ng+32,ng+48} ×
// columns {cg,cg+16,...}: per 2-k-step 4 broadcast ds_read_b64 + NT
// coalesced 8B Wp loads + 8*NT FMAs.
template<int FI, int FO, int IN_BN, int IN_F32, int OUT_F32>
__global__ __launch_bounds__(256)
void k_dense(const void* __restrict__ Xv, const float* __restrict__ Wp,
             const float* __restrict__ biasf, void* __restrict__ Hv) {
    constexpr int NT  = (FO + 15) / 16;
    constexpr int FOP = 16 * NT;
    constexpr int FIP = FI + 2;   // even pad: ng bank-stride odd*2 -> distinct banks
    constexpr int KP  = FI / 2;

    __shared__ __align__(16) float xs[64 * FIP];

    int tid = threadIdx.x;
    int node0 = blockIdx.x * 64;

    // ---- stage X tile (coalesced) ----
    if (IN_F32) {
        for (int idx = tid; idx < 64 * FI; idx += 256) {
            int r = idx / FI, c = idx - r * FI;
            int n = node0 + r;
            float v = (n < NN) ? ((const float*)Xv)[(size_t)n * FI + c] : 0.0f;
            if (IN_BN) v = fmaxf(v, 0.0f);
            xs[r * FIP + c] = v;
        }
    } else {
        for (int idx = tid; idx < 64 * KP; idx += 256) {
            int r = idx / KP, c2 = idx - r * KP;
            int n = node0 + r;
            uint_t u = (n < NN) ? ((const uint_t*)Xv)[(size_t)n * KP + c2] : 0u;
            float f0 = bflo(u), f1 = bfhi(u);
            if (IN_BN) { f0 = fmaxf(f0, 0.0f); f1 = fmaxf(f1, 0.0f); }
            xs[r * FIP + 2 * c2]     = f0;
            xs[r * FIP + 2 * c2 + 1] = f1;
        }
    }
    __syncthreads();

    int ng = tid >> 4;      // 0..15 -> node subset {ng, ng+16, ng+32, ng+48}
    int cg = tid & 15;      // 0..15 -> columns {cg + 16*t}

    float acc[4][NT];
    #pragma unroll
    for (int i = 0; i < 4; ++i)
        #pragma unroll
        for (int t = 0; t < NT; ++t) acc[i][t] = biasf[cg + 16 * t];

    #pragma unroll 2
    for (int k = 0; k < FI; k += 2) {
        float2 xv[4];
        #pragma unroll
        for (int i = 0; i < 4; ++i)
            xv[i] = *(const float2*)&xs[(ng + 16 * i) * FIP + k];
        const float* wrow = &Wp[(k >> 1) * 2 * FOP];
        #pragma unroll
        for (int t = 0; t < NT; ++t) {
            float2 w = *(const float2*)&wrow[2 * (cg + 16 * t)];
            #pragma unroll
            for (int i = 0; i < 4; ++i)
                acc[i][t] = fmaf(xv[i].y, w.y, fmaf(xv[i].x, w.x, acc[i][t]));
        }
    }

    // ---- store (coalesced 16-lane segments) ----
    #pragma unroll
    for (int i = 0; i < 4; ++i) {
        int n = node0 + ng + 16 * i;
        if (n < NN) {
            #pragma unroll
            for (int t = 0; t < NT; ++t) {
                int j = cg + 16 * t;
                if (j < FO) {
                    if (OUT_F32) ((float*)Hv)[(size_t)n * FO + j] = acc[i][t];
                    else ((ushort_t*)Hv)[(size_t)n * FO + j] = packbf1(acc[i][t]);
                }
            }
        }
    }
}

// ---------------- CSR gather (bf16 in/out, unroll-8) ----------------
template<int FO, int IN_BN, int OUT_BIAS>
__global__ void k_gather(const ushort_t* __restrict__ h, const int* __restrict__ row_ptr,
                         const int* __restrict__ col, const float* __restrict__ wgt,
                         const float* __restrict__ dis,
                         const float* __restrict__ bnacc, const float* __restrict__ g,
                         const float* __restrict__ be,
                         const float* __restrict__ b, ushort_t* __restrict__ A) {
    constexpr int F2 = FO / 2;
    int t = blockIdx.x * blockDim.x + threadIdx.x;
    if (t >= NN * F2) return;
    int i = t / F2;
    int j2 = t - i * F2;
    int j = 2 * j2;

    float sc0 = 1.0f, sh0 = 0.0f, sc1 = 1.0f, sh1 = 0.0f;
    if (IN_BN) {
        const float inv_n = 1.0f / NN;
        float mu0 = bnacc[j] * inv_n;
        float va0 = bnacc[96 + j] * inv_n - mu0 * mu0;
        float r0  = rsqrtf(va0 + 1e-5f);
        sc0 = g[j] * r0; sh0 = be[j] - mu0 * sc0;
        float mu1 = bnacc[j + 1] * inv_n;
        float va1 = bnacc[96 + j + 1] * inv_n - mu1 * mu1;
        float r1  = rsqrtf(va1 + 1e-5f);
        sc1 = g[j + 1] * r1; sh1 = be[j + 1] - mu1 * sc1;
    }

    const uint_t* h2 = (const uint_t*)h + j2;  // column pair j within rows
    float di = dis[i];

    // self-loop
    uint_t su = h2[(size_t)i * F2];
    float vx = bflo(su), vy = bfhi(su);
    if (IN_BN) { vx = fmaxf(vx, 0.0f) * sc0 + sh0; vy = fmaxf(vy, 0.0f) * sc1 + sh1; }
    float ax = vx * di * di;
    float ay = vy * di * di;

    int k = row_ptr[i], end = row_ptr[i + 1];
    for (; k + 8 <= end; k += 8) {
        uint_t uu[8]; float ww[8];
        #pragma unroll
        for (int q = 0; q < 8; ++q) {
            int s = col[k + q];
            ww[q] = wgt[k + q];
            uu[q] = h2[(size_t)s * F2];
        }
        #pragma unroll
        for (int q = 0; q < 8; ++q) {
            float tx = bflo(uu[q]), ty = bfhi(uu[q]);
            if (IN_BN) { tx = fmaxf(tx, 0.0f) * sc0 + sh0; ty = fmaxf(ty, 0.0f) * sc1 + sh1; }
            ax = fmaf(tx, ww[q], ax); ay = fmaf(ty, ww[q], ay);
        }
    }
    for (; k < end; ++k) {
        int s = col[k];
        float w = wgt[k];
        uint_t u = h2[(size_t)s * F2];
        float tx = bflo(u), ty = bfhi(u);
        if (IN_BN) { tx = fmaxf(tx, 0.0f) * sc0 + sh0; ty = fmaxf(ty, 0.0f) * sc1 + sh1; }
        ax = fmaf(tx, w, ax); ay = fmaf(ty, w, ay);
    }
    if (OUT_BIAS) { ax += b[j]; ay += b[j + 1]; }
    ((uint_t*)A)[(size_t)i * F2 + j2] = packbf(ax, ay);
}

// ---------------- BN partial sums over relu(A), bf16 input ----------------
template<int FO>
__global__ void k_bnpart(const ushort_t* __restrict__ A, float* __restrict__ acc) {
    constexpr int F2 = FO / 2;
    __shared__ float ls[96], lq[96];
    int tid = threadIdx.x;
    if (tid < 96) { ls[tid] = 0.0f; lq[tid] = 0.0f; }
    __syncthreads();
    const uint_t* A2 = (const uint_t*)A;
    int t2 = blockIdx.x * blockDim.x + tid;
    int j2 = t2 % F2;
    int stride = gridDim.x * blockDim.x;
    float sx = 0.0f, qx = 0.0f, sy = 0.0f, qy = 0.0f;
    for (; t2 < NN * F2; t2 += stride) {
        uint_t u = A2[t2];
        float x = fmaxf(bflo(u), 0.0f), y = fmaxf(bfhi(u), 0.0f);
        sx += x; qx += x * x;
        sy += y; qy += y * y;
    }
    atomicAdd(&ls[2 * j2], sx);     atomicAdd(&ls[2 * j2 + 1], sy);
    atomicAdd(&lq[2 * j2], qx);     atomicAdd(&lq[2 * j2 + 1], qy);
    __syncthreads();
    if (tid < FO) {
        atomicAdd(&acc[tid], ls[tid]);
        atomicAdd(&acc[96 + tid], lq[tid]);
    }
}

extern "C" void kernel_launch(void* const* d_in, const int* in_sizes, int n_in,
                              void* d_out, int out_size, void* d_ws, size_t ws_size,
                              hipStream_t stream) {
    const float* x = (const float*)d_in[0];
    const int* ei = (const int*)d_in[1];
    const int* src = ei;             // edge_index[0]
    const int* dst = ei + NE;        // edge_index[1]
    const float* W1 = (const float*)d_in[2];  const float* b1 = (const float*)d_in[3];
    const float* W2 = (const float*)d_in[4];  const float* b2 = (const float*)d_in[5];
    const float* W3 = (const float*)d_in[6];  const float* b3 = (const float*)d_in[7];
    const float* W4 = (const float*)d_in[8];  const float* b4 = (const float*)d_in[9];
    const float* W5 = (const float*)d_in[10]; const float* b5 = (const float*)d_in[11];
    const float* W6 = (const float*)d_in[12]; const float* b6 = (const float*)d_in[13];
    const float* g1 = (const float*)d_in[14]; const float* be1 = (const float*)d_in[15];
    const float* g2 = (const float*)d_in[16]; const float* be2 = (const float*)d_in[17];
    const float* g3 = (const float*)d_in[18]; const float* be3 = (const float*)d_in[19];
    const float* g4 = (const float*)d_in[20]; const float* be4 = (const float*)d_in[21];

    // workspace (~21.6 MB)
    float* ws = (float*)d_ws;
    float* dis    = ws;                         // NN
    float* bnacc  = dis + NN;                   // 768
    float* Wp     = bnacc + 768;                // 7040 (max FI*FOP), 8B-aligned
    float* biasf  = Wp + 7040;                  // 96
    float* wgt    = biasf + 96;                 // NE
    int* deg      = (int*)(wgt + NE);           // NN
    int* row_ptr  = deg + NN;                   // NN+1
    int* cursor   = row_ptr + NN + 1;           // NN
    int* col      = cursor + NN;                // NE
    int* bsum     = col + NE;                   // 256
    int* boff     = bsum + 256;                 // 256
    ushort_t* hB  = (ushort_t*)(boff + 256);    // NN*70 bf16
    ushort_t* aB  = hB + (size_t)NN * 70;       // NN*70 bf16
    float* out    = (float*)d_out;

    const int NB = 256;
    const int DGRID = cdiv(NN, 64);
    float* bn0 = bnacc;        // L1 stats (g1,be1)
    float* bn1 = bnacc + 192;  // L2 stats (g2,be2)
    float* bn2 = bnacc + 384;  // L4 stats (g3,be3)
    float* bn3 = bnacc + 576;  // L5 stats (g4,be4)

    // ---- CSR + normalization build ----
    k_prep<<<cdiv(NN, NB), NB, 0, stream>>>(deg, bnacc);
    k_hist<<<cdiv(NE, NB), NB, 0, stream>>>(dst, deg);
    k_bsum<<<NBLK, 256, 0, stream>>>(deg, bsum);
    k_bscan<<<1, 256, 0, stream>>>(bsum, boff, row_ptr);
    k_rowptr<<<NBLK, 256, 0, stream>>>(deg, boff, row_ptr, cursor, dis);
    k_fill<<<cdiv(NE, NB), NB, 0, stream>>>(src, dst, dis, cursor, col, wgt);

    // ---- L1: dense x(88,f32)->hB(70); gather hB -> aB + b1; stats bn0 ----
    k_fold<88, 70, 0, 0><<<1, 256, 0, stream>>>(nullptr, nullptr, nullptr, nullptr, W1, Wp, biasf);
    k_dense<88, 70, 0, 1, 0><<<DGRID, 256, 0, stream>>>(x, Wp, biasf, hB);
    k_gather<70, 0, 1><<<cdiv((long long)NN * 35, NB), NB, 0, stream>>>(
        hB, row_ptr, col, wgt, dis, nullptr, nullptr, nullptr, b1, aB);
    k_bnpart<70><<<35 * 56, NB, 0, stream>>>(aB, bn0);

    // ---- L2: dense bn(aB)(70)->hB(60); gather hB -> aB + b2; stats bn1 ----
    k_fold<70, 60, 1, 0><<<1, 256, 0, stream>>>(bn0, g1, be1, nullptr, W2, Wp, biasf);
    k_dense<70, 60, 1, 0, 0><<<DGRID, 256, 0, stream>>>(aB, Wp, biasf, hB);
    k_gather<60, 0, 1><<<cdiv((long long)NN * 30, NB), NB, 0, stream>>>(
        hB, row_ptr, col, wgt, dis, nullptr, nullptr, nullptr, b2, aB);
    k_bnpart<60><<<30 * 56, NB, 0, stream>>>(aB, bn1);

    // ---- L3: dense bn(aB)(60)->hB(50); gather hB -> aB + b3 (A3) ----
    k_fold<60, 50, 1, 0><<<1, 256, 0, stream>>>(bn1, g2, be2, nullptr, W3, Wp, biasf);
    k_dense<60, 50, 1, 0, 0><<<DGRID, 256, 0, stream>>>(aB, Wp, biasf, hB);
    k_gather<50, 0, 1><<<cdiv((long long)NN * 25, NB), NB, 0, stream>>>(
        hB, row_ptr, col, wgt, dis, nullptr, nullptr, nullptr, b3, aB);

    // ---- L4 (aggregate-first): gather aB(A3) -> hB(agg4,50); dense hB -> aB(A4,60)+b4; stats bn2 ----
    k_gather<50, 0, 0><<<cdiv((long long)NN * 25, NB), NB, 0, stream>>>(
        aB, row_ptr, col, wgt, dis, nullptr, nullptr, nullptr, nullptr, hB);
    k_fold<50, 60, 0, 1><<<1, 256, 0, stream>>>(nullptr, nullptr, nullptr, b4, W4, Wp, biasf);
    k_dense<50, 60, 0, 0, 0><<<DGRID, 256, 0, stream>>>(hB, Wp, biasf, aB);
    k_bnpart<60><<<30 * 56, NB, 0, stream>>>(aB, bn2);

    // ---- L5: gather bn(aB=A4) -> hB(agg5,60); dense hB -> aB(A5,70)+b5; stats bn3 ----
    k_gather<60, 1, 0><<<cdiv((long long)NN * 30, NB), NB, 0, stream>>>(
        aB, row_ptr, col, wgt, dis, bn2, g3, be3, nullptr, hB);
    k_fold<60, 70, 0, 1><<<1, 256, 0, stream>>>(nullptr, nullptr, nullptr, b5, W5, Wp, biasf);
    k_dense<60, 70, 0, 0, 0><<<DGRID, 256, 0, stream>>>(hB, Wp, biasf, aB);
    k_bnpart<70><<<35 * 56, NB, 0, stream>>>(aB, bn3);

    // ---- L6: gather bn(aB=A5) -> hB(agg6,70); dense hB -> out(88,f32)+b6 ----
    k_gather<70, 1, 0><<<cdiv((long long)NN * 35, NB), NB, 0, stream>>>(
        aB, row_ptr, col, wgt, dis, bn3, g4, be4, nullptr, hB);
    k_fold<70, 88, 0, 1><<<1, 256, 0, stream>>>(nullptr, nullptr, nullptr, b6, W6, Wp, biasf);
    k_dense<70, 88, 0, 0, 1><<<DGRID, 256, 0, stream>>>(hB, Wp, biasf, out);
}

// Round 9
// 557.287 us; speedup vs baseline: 2.8789x; 1.1916x over previous
//
#include <hip/hip_runtime.h>
#include <hip/hip_bf16.h>

typedef unsigned int  uint_t;
typedef unsigned short ushort_t;

#define NN 50000
#define NE 800000
#define NBLK 196   // cdiv(NN,256) for CSR kernels

static inline int cdiv(long long a, long long b) { return (int)((a + b - 1) / b); }

// ---- bf16 pair helpers (element j at low 16 bits) ----
__device__ inline float bflo(uint_t u) { return __uint_as_float(u << 16); }
__device__ inline float bfhi(uint_t u) { return __uint_as_float(u & 0xffff0000u); }
__device__ inline uint_t packbf(float x, float y) {  // RNE
    uint_t xu = __float_as_uint(x), yu = __float_as_uint(y);
    xu += 0x7fffu + ((xu >> 16) & 1u);
    yu += 0x7fffu + ((yu >> 16) & 1u);
    return (xu >> 16) | (yu & 0xffff0000u);
}
__device__ inline ushort_t packbf1(float x) {
    uint_t xu = __float_as_uint(x);
    xu += 0x7fffu + ((xu >> 16) & 1u);
    return (ushort_t)(xu >> 16);
}

// ---------------- CSR build ----------------

__global__ void k_prep(int* __restrict__ deg, float* __restrict__ bnacc) {
    int i = blockIdx.x * blockDim.x + threadIdx.x;
    if (i < NN) deg[i] = 0;
    if (i < 768) bnacc[i] = 0.0f;
}

__global__ void k_hist(const int* __restrict__ dst, int* __restrict__ deg) {
    int e = blockIdx.x * blockDim.x + threadIdx.x;
    if (e < NE) {
        int d = dst[e];
        if ((unsigned)d < NN) atomicAdd(&deg[d], 1);
    }
}

__global__ void k_bsum(const int* __restrict__ deg, int* __restrict__ bsum) {
    __shared__ int l[256];
    int tid = threadIdx.x;
    int i = blockIdx.x * 256 + tid;
    l[tid] = (i < NN) ? deg[i] : 0;
    __syncthreads();
    for (int o = 128; o > 0; o >>= 1) {
        if (tid < o) l[tid] += l[tid + o];
        __syncthreads();
    }
    if (tid == 0) bsum[blockIdx.x] = l[0];
}

__global__ void k_bscan(const int* __restrict__ bsum, int* __restrict__ boff,
                        int* __restrict__ row_ptr) {
    __shared__ int l[256];
    int tid = threadIdx.x;
    int v = (tid < NBLK) ? bsum[tid] : 0;
    l[tid] = v;
    __syncthreads();
    for (int o = 1; o < 256; o <<= 1) {
        int t = (tid >= o) ? l[tid - o] : 0;
        __syncthreads();
        l[tid] += t;
        __syncthreads();
    }
    boff[tid] = l[tid] - v;            // exclusive block offset
    if (tid == 255) row_ptr[NN] = l[255];  // total
}

__global__ void k_rowptr(const int* __restrict__ deg, const int* __restrict__ boff,
                         int* __restrict__ row_ptr, int* __restrict__ cursor,
                         float* __restrict__ dis) {
    __shared__ int l[256];
    int tid = threadIdx.x;
    int i = blockIdx.x * 256 + tid;
    int v = (i < NN) ? deg[i] : 0;
    l[tid] = v;
    __syncthreads();
    for (int o = 1; o < 256; o <<= 1) {
        int t = (tid >= o) ? l[tid - o] : 0;
        __syncthreads();
        l[tid] += t;
        __syncthreads();
    }
    if (i < NN) {
        int excl = boff[blockIdx.x] + l[tid] - v;
        row_ptr[i] = excl;
        cursor[i] = excl;
        dis[i] = rsqrtf((float)(v + 1));  // +1 self-loop
    }
}

// packed (col, wgt) fill: ONE 8B random store per edge
__global__ void k_fill(const int* __restrict__ src, const int* __restrict__ dst,
                       const float* __restrict__ dis,
                       int* __restrict__ cursor, int2* __restrict__ cw) {
    int e = blockIdx.x * blockDim.x + threadIdx.x;
    if (e < NE) {
        int s = src[e], d = dst[e];
        if ((unsigned)s < NN && (unsigned)d < NN) {
            int p = atomicAdd(&cursor[d], 1);
            cw[p] = make_int2(s, __float_as_int(dis[s] * dis[d]));
        }
    }
}

// ---------------- generic weight fold/pad (runtime dims) ----------------
// Wp layout (k-pair interleaved, padded to FOP=16*NT cols):
//   Wp[(k/2)*2*FOP + 2*j + (k&1)] = W[k][j] * (in_bn ? scl[k] : 1), j<FO else 0
// bf[j] = (out_b ? b[j] : 0) + (in_bn ? sum_k shl[k]*W[k][j] : 0)
struct FoldJob {
    const float* W; const float* b;
    const float* bnacc; const float* g; const float* be;
    float* Wp; float* bf;
    int FI, FO, in_bn, out_b;
};
struct FoldJobs { FoldJob j[4]; };

__global__ void k_fold(FoldJobs jobs) {
    FoldJob J = jobs.j[blockIdx.x];
    const int FI = J.FI, FO = J.FO;
    const int NT = (FO + 15) / 16, FOP = 16 * NT;
    __shared__ float scl[96], shl[96];
    int tid = threadIdx.x;
    if (J.in_bn) {
        if (tid < FI) {
            const float inv_n = 1.0f / NN;
            float mu = J.bnacc[tid] * inv_n;
            float va = J.bnacc[96 + tid] * inv_n - mu * mu;
            float r  = rsqrtf(va + 1e-5f);
            float sc = J.g[tid] * r;
            scl[tid] = sc;
            shl[tid] = J.be[tid] - mu * sc;
        }
        __syncthreads();
    }
    for (int idx = tid; idx < FI * FOP; idx += 256) {
        int k = idx / FOP, j = idx - k * FOP;
        float w = (j < FO) ? J.W[k * FO + j] : 0.0f;
        if (J.in_bn) w *= scl[k];
        J.Wp[(k >> 1) * 2 * FOP + 2 * j + (k & 1)] = w;
    }
    if (tid < FOP) {
        float a = (J.out_b && tid < FO) ? J.b[tid] : 0.0f;
        if (J.in_bn && tid < FO) {
            for (int k = 0; k < FI; ++k) a = fmaf(shl[k], J.W[k * FO + tid], a);
        }
        J.bf[tid] = a;
    }
}

// ---------------- dense: H = in_tf(X) @ Wp + biasf ----------------
// 64 nodes per block, 256 threads; register-tiled 4 nodes x NT cols per
// thread. OUT_BN: accumulate relu stats of output into bnst (LDS reduce +
// per-block global atomics).
template<int FI, int FO, int IN_BN, int IN_F32, int OUT_F32, int OUT_BN>
__global__ __launch_bounds__(256)
void k_dense(const void* __restrict__ Xv, const float* __restrict__ Wp,
             const float* __restrict__ biasf, void* __restrict__ Hv,
             float* __restrict__ bnst) {
    constexpr int NT  = (FO + 15) / 16;
    constexpr int FOP = 16 * NT;
    constexpr int FIP = FI + 2;   // even pad: ng bank-stride odd*2 -> distinct banks
    constexpr int KP  = FI / 2;

    __shared__ __align__(16) float xs[64 * FIP];
    __shared__ float ls[96], lq[96];

    int tid = threadIdx.x;
    int node0 = blockIdx.x * 64;

    if (OUT_BN) {
        if (tid < 96) { ls[tid] = 0.0f; lq[tid] = 0.0f; }
    }

    // ---- stage X tile (coalesced) ----
    if (IN_F32) {
        for (int idx = tid; idx < 64 * FI; idx += 256) {
            int r = idx / FI, c = idx - r * FI;
            int n = node0 + r;
            float v = (n < NN) ? ((const float*)Xv)[(size_t)n * FI + c] : 0.0f;
            if (IN_BN) v = fmaxf(v, 0.0f);
            xs[r * FIP + c] = v;
        }
    } else {
        for (int idx = tid; idx < 64 * KP; idx += 256) {
            int r = idx / KP, c2 = idx - r * KP;
            int n = node0 + r;
            uint_t u = (n < NN) ? ((const uint_t*)Xv)[(size_t)n * KP + c2] : 0u;
            float f0 = bflo(u), f1 = bfhi(u);
            if (IN_BN) { f0 = fmaxf(f0, 0.0f); f1 = fmaxf(f1, 0.0f); }
            xs[r * FIP + 2 * c2]     = f0;
            xs[r * FIP + 2 * c2 + 1] = f1;
        }
    }
    __syncthreads();

    int ng = tid >> 4;      // 0..15 -> nodes {ng, ng+16, ng+32, ng+48}
    int cg = tid & 15;      // 0..15 -> columns {cg + 16*t}

    float acc[4][NT];
    #pragma unroll
    for (int i = 0; i < 4; ++i)
        #pragma unroll
        for (int t = 0; t < NT; ++t) acc[i][t] = biasf[cg + 16 * t];

    #pragma unroll 2
    for (int k = 0; k < FI; k += 2) {
        float2 xv[4];
        #pragma unroll
        for (int i = 0; i < 4; ++i)
            xv[i] = *(const float2*)&xs[(ng + 16 * i) * FIP + k];
        const float* wrow = &Wp[(k >> 1) * 2 * FOP];
        #pragma unroll
        for (int t = 0; t < NT; ++t) {
            float2 w = *(const float2*)&wrow[2 * (cg + 16 * t)];
            #pragma unroll
            for (int i = 0; i < 4; ++i)
                acc[i][t] = fmaf(xv[i].y, w.y, fmaf(xv[i].x, w.x, acc[i][t]));
        }
    }

    // ---- fused BN stats over relu(output) ----
    if (OUT_BN) {
        #pragma unroll
        for (int t = 0; t < NT; ++t) {
            float ps = 0.0f, pq = 0.0f;
            #pragma unroll
            for (int i = 0; i < 4; ++i) {
                if (node0 + ng + 16 * i < NN) {
                    float r = fmaxf(acc[i][t], 0.0f);
                    ps += r; pq += r * r;
                }
            }
            atomicAdd(&ls[cg + 16 * t], ps);
            atomicAdd(&lq[cg + 16 * t], pq);
        }
        __syncthreads();
        if (tid < FO) {
            atomicAdd(&bnst[tid], ls[tid]);
            atomicAdd(&bnst[96 + tid], lq[tid]);
        }
    }

    // ---- store (coalesced 16-lane segments) ----
    #pragma unroll
    for (int i = 0; i < 4; ++i) {
        int n = node0 + ng + 16 * i;
        if (n < NN) {
            #pragma unroll
            for (int t = 0; t < NT; ++t) {
                int j = cg + 16 * t;
                if (j < FO) {
                    if (OUT_F32) ((float*)Hv)[(size_t)n * FO + j] = acc[i][t];
                    else ((ushort_t*)Hv)[(size_t)n * FO + j] = packbf1(acc[i][t]);
                }
            }
        }
    }
}

// ---------------- CSR gather (bf16 in/out, unroll-8, packed cw) ----------------
// OUT_BN: grid-strided (grid = 56*F2 so stride % F2 == 0 -> fixed j2/thread),
// accumulates relu stats of output into bnacc_out.
template<int FO, int IN_BN, int OUT_BIAS, int OUT_BN>
__global__ void k_gather(const ushort_t* __restrict__ h, const int* __restrict__ row_ptr,
                         const int2* __restrict__ cw, const float* __restrict__ dis,
                         const float* __restrict__ bnacc, const float* __restrict__ g,
                         const float* __restrict__ be,
                         const float* __restrict__ b, ushort_t* __restrict__ A,
                         float* __restrict__ bnacc_out) {
    constexpr int F2 = FO / 2;
    __shared__ float ls[96], lq[96];
    int tid = threadIdx.x;
    if (OUT_BN) {
        if (tid < 96) { ls[tid] = 0.0f; lq[tid] = 0.0f; }
        __syncthreads();
    }

    int t0 = blockIdx.x * blockDim.x + tid;
    const int stride = gridDim.x * blockDim.x;
    int j2 = t0 % F2;       // constant across strides (stride % F2 == 0 for OUT_BN)
    int j = 2 * j2;

    float sc0 = 1.0f, sh0 = 0.0f, sc1 = 1.0f, sh1 = 0.0f;
    if (IN_BN) {
        const float inv_n = 1.0f / NN;
        float mu0 = bnacc[j] * inv_n;
        float va0 = bnacc[96 + j] * inv_n - mu0 * mu0;
        float r0  = rsqrtf(va0 + 1e-5f);
        sc0 = g[j] * r0; sh0 = be[j] - mu0 * sc0;
        float mu1 = bnacc[j + 1] * inv_n;
        float va1 = bnacc[96 + j + 1] * inv_n - mu1 * mu1;
        float r1  = rsqrtf(va1 + 1e-5f);
        sc1 = g[j + 1] * r1; sh1 = be[j + 1] - mu1 * sc1;
    }

    const uint_t* h2 = (const uint_t*)h + j2;  // column pair j within rows
    float sx = 0.0f, qx = 0.0f, sy = 0.0f, qy = 0.0f;

    for (int t = t0; t < NN * F2; t += stride) {
        int i = t / F2;
        float di = dis[i];

        // self-loop
        uint_t su = h2[(size_t)i * F2];
        float vx = bflo(su), vy = bfhi(su);
        if (IN_BN) { vx = fmaxf(vx, 0.0f) * sc0 + sh0; vy = fmaxf(vy, 0.0f) * sc1 + sh1; }
        float ax = vx * di * di;
        float ay = vy * di * di;

        int k = row_ptr[i], end = row_ptr[i + 1];
        for (; k + 8 <= end; k += 8) {
            uint_t uu[8]; float ww[8];
            #pragma unroll
            for (int q = 0; q < 8; ++q) {
                int2 c = cw[k + q];
                ww[q] = __int_as_float(c.y);
                uu[q] = h2[(size_t)c.x * F2];
            }
            #pragma unroll
            for (int q = 0; q < 8; ++q) {
                float tx = bflo(uu[q]), ty = bfhi(uu[q]);
                if (IN_BN) { tx = fmaxf(tx, 0.0f) * sc0 + sh0; ty = fmaxf(ty, 0.0f) * sc1 + sh1; }
                ax = fmaf(tx, ww[q], ax); ay = fmaf(ty, ww[q], ay);
            }
        }
        for (; k < end; ++k) {
            int2 c = cw[k];
            float w = __int_as_float(c.y);
            uint_t u = h2[(size_t)c.x * F2];
            float tx = bflo(u), ty = bfhi(u);
            if (IN_BN) { tx = fmaxf(tx, 0.0f) * sc0 + sh0; ty = fmaxf(ty, 0.0f) * sc1 + sh1; }
            ax = fmaf(tx, w, ax); ay = fmaf(ty, w, ay);
        }
        if (OUT_BIAS) { ax += b[j]; ay += b[j + 1]; }
        if (OUT_BN) {
            float rx = fmaxf(ax, 0.0f), ry = fmaxf(ay, 0.0f);
            sx += rx; qx += rx * rx;
            sy += ry; qy += ry * ry;
        }
        ((uint_t*)A)[(size_t)i * F2 + j2] = packbf(ax, ay);
    }

    if (OUT_BN) {
        atomicAdd(&ls[j], sx);     atomicAdd(&ls[j + 1], sy);
        atomicAdd(&lq[j], qx);     atomicAdd(&lq[j + 1], qy);
        __syncthreads();
        if (tid < FO) {
            atomicAdd(&bnacc_out[tid], ls[tid]);
            atomicAdd(&bnacc_out[96 + tid], lq[tid]);
        }
    }
}

extern "C" void kernel_launch(void* const* d_in, const int* in_sizes, int n_in,
                              void* d_out, int out_size, void* d_ws, size_t ws_size,
                              hipStream_t stream) {
    const float* x = (const float*)d_in[0];
    const int* ei = (const int*)d_in[1];
    const int* src = ei;             // edge_index[0]
    const int* dst = ei + NE;        // edge_index[1]
    const float* W1 = (const float*)d_in[2];  const float* b1 = (const float*)d_in[3];
    const float* W2 = (const float*)d_in[4];  const float* b2 = (const float*)d_in[5];
    const float* W3 = (const float*)d_in[6];  const float* b3 = (const float*)d_in[7];
    const float* W4 = (const float*)d_in[8];  const float* b4 = (const float*)d_in[9];
    const float* W5 = (const float*)d_in[10]; const float* b5 = (const float*)d_in[11];
    const float* W6 = (const float*)d_in[12]; const float* b6 = (const float*)d_in[13];
    const float* g1 = (const float*)d_in[14]; const float* be1 = (const float*)d_in[15];
    const float* g2 = (const float*)d_in[16]; const float* be2 = (const float*)d_in[17];
    const float* g3 = (const float*)d_in[18]; const float* be3 = (const float*)d_in[19];
    const float* g4 = (const float*)d_in[20]; const float* be4 = (const float*)d_in[21];

    // workspace (~21.5 MB)
    float* ws = (float*)d_ws;
    float* dis    = ws;                          // NN
    float* bnacc  = dis + NN;                    // 768
    float* Wp     = bnacc + 768;                 // 6 * 7040
    float* biasf  = Wp + 6 * 7040;               // 6 * 96
    int2* cw      = (int2*)(biasf + 6 * 96);     // NE (8B aligned)
    int* deg      = (int*)(cw + NE);             // NN
    int* row_ptr  = deg + NN;                    // NN+1
    int* cursor   = row_ptr + NN + 1;            // NN
    int* bsum     = cursor + NN;                 // 256
    int* boff     = bsum + 256;                  // 256
    ushort_t* hB  = (ushort_t*)(boff + 256);     // NN*70 bf16
    ushort_t* aB  = hB + (size_t)NN * 70;        // NN*70 bf16
    float* out    = (float*)d_out;

    const int NB = 256;
    const int DGRID = cdiv(NN, 64);
    float* bn0 = bnacc;        // L1 stats (g1,be1)
    float* bn1 = bnacc + 192;  // L2 stats (g2,be2)
    float* bn2 = bnacc + 384;  // L4 stats (g3,be3)
    float* bn3 = bnacc + 576;  // L5 stats (g4,be4)
    float* WpL[6]; float* bfL[6];
    for (int i = 0; i < 6; ++i) { WpL[i] = Wp + i * 7040; bfL[i] = biasf + i * 96; }

    // ---- CSR + normalization build ----
    k_prep<<<cdiv(NN, NB), NB, 0, stream>>>(deg, bnacc);
    k_hist<<<cdiv(NE, NB), NB, 0, stream>>>(dst, deg);
    k_bsum<<<NBLK, 256, 0, stream>>>(deg, bsum);
    k_bscan<<<1, 256, 0, stream>>>(bsum, boff, row_ptr);
    k_rowptr<<<NBLK, 256, 0, stream>>>(deg, boff, row_ptr, cursor, dis);
    k_fill<<<cdiv(NE, NB), NB, 0, stream>>>(src, dst, dis, cursor, cw);

    // ---- fold the 4 BN-independent layers (L1,L4,L5,L6) in one launch ----
    {
        FoldJobs js;
        js.j[0] = {W1, nullptr, nullptr, nullptr, nullptr, WpL[0], bfL[0], 88, 70, 0, 0};
        js.j[1] = {W4, b4,      nullptr, nullptr, nullptr, WpL[3], bfL[3], 50, 60, 0, 1};
        js.j[2] = {W5, b5,      nullptr, nullptr, nullptr, WpL[4], bfL[4], 60, 70, 0, 1};
        js.j[3] = {W6, b6,      nullptr, nullptr, nullptr, WpL[5], bfL[5], 70, 88, 0, 1};
        k_fold<<<4, 256, 0, stream>>>(js);
    }

    // ---- L1: dense x(88,f32)->hB(70); gather+bn0: hB -> aB + b1 ----
    k_dense<88, 70, 0, 1, 0, 0><<<DGRID, 256, 0, stream>>>(x, WpL[0], bfL[0], hB, nullptr);
    k_gather<70, 0, 1, 1><<<56 * 35, NB, 0, stream>>>(
        hB, row_ptr, cw, dis, nullptr, nullptr, nullptr, b1, aB, bn0);

    // ---- L2: fold(bn0); dense relu(aB)(70)->hB(60); gather+bn1: hB -> aB + b2 ----
    {
        FoldJobs js;
        js.j[0] = {W2, nullptr, bn0, g1, be1, WpL[1], bfL[1], 70, 60, 1, 0};
        k_fold<<<1, 256, 0, stream>>>(js);
    }
    k_dense<70, 60, 1, 0, 0, 0><<<DGRID, 256, 0, stream>>>(aB, WpL[1], bfL[1], hB, nullptr);
    k_gather<60, 0, 1, 1><<<56 * 30, NB, 0, stream>>>(
        hB, row_ptr, cw, dis, nullptr, nullptr, nullptr, b2, aB, bn1);

    // ---- L3: fold(bn1); dense relu(aB)(60)->hB(50); gather: hB -> aB + b3 ----
    {
        FoldJobs js;
        js.j[0] = {W3, nullptr, bn1, g2, be2, WpL[2], bfL[2], 60, 50, 1, 0};
        k_fold<<<1, 256, 0, stream>>>(js);
    }
    k_dense<60, 50, 1, 0, 0, 0><<<DGRID, 256, 0, stream>>>(aB, WpL[2], bfL[2], hB, nullptr);
    k_gather<50, 0, 1, 0><<<cdiv((long long)NN * 25, NB), NB, 0, stream>>>(
        hB, row_ptr, cw, dis, nullptr, nullptr, nullptr, b3, aB, nullptr);

    // ---- L4 (aggregate-first): gather aB(A3)->hB(50); dense+bn2: hB->aB(60)+b4 ----
    k_gather<50, 0, 0, 0><<<cdiv((long long)NN * 25, NB), NB, 0, stream>>>(
        aB, row_ptr, cw, dis, nullptr, nullptr, nullptr, nullptr, hB, nullptr);
    k_dense<50, 60, 0, 0, 0, 1><<<DGRID, 256, 0, stream>>>(hB, WpL[3], bfL[3], aB, bn2);

    // ---- L5: gather bn2(relu(aB))->hB(60); dense+bn3: hB->aB(70)+b5 ----
    k_gather<60, 1, 0, 0><<<cdiv((long long)NN * 30, NB), NB, 0, stream>>>(
        aB, row_ptr, cw, dis, bn2, g3, be3, nullptr, hB, nullptr);
    k_dense<60, 70, 0, 0, 0, 1><<<DGRID, 256, 0, stream>>>(hB, WpL[4], bfL[4], aB, bn3);

    // ---- L6: gather bn3(relu(aB))->hB(70); dense: hB->out(88,f32)+b6 ----
    k_gather<70, 1, 0, 0><<<cdiv((long long)NN * 35, NB), NB, 0, stream>>>(
        aB, row_ptr, cw, dis, bn3, g4, be4, nullptr, hB, nullptr);
    k_dense<70, 88, 0, 0, 1, 0><<<DGRID, 256, 0, stream>>>(hB, WpL[5], bfL[5], out, nullptr);
}